// Round 12
// baseline (289.667 us; speedup 1.0000x reference)
//
#include <hip/hip_runtime.h>
#include <math.h>

#define T_DIM 64
#define C_DIM 256
#define H_DIM 56
#define W_DIM 56
#define HW    (H_DIM * W_DIM)        // 3136
#define HW4   (HW / 4)               // 784
#define CHW   (C_DIM * HW)
#define THW   (T_DIM * HW)           // 200704

typedef float nt_float4 __attribute__((ext_vector_type(4)));

// force a (wave-uniform) float into an SGPR
__device__ __forceinline__ float rfl(float v) {
    return __int_as_float(__builtin_amdgcn_readfirstlane(__float_as_int(v)));
}

// ---------------------------------------------------------------------------
// Kernel 1 (1024 threads/block): fused gate conv + c>=128 copy.
// Gate blocks [0,256): block = (side, t, hh); 16 waves = 16 groups of 4 ch
//   (same short latency chain as the best two-stage version). LDS log-tree
//   reduce (16->8->4->2->1, 57KB buffer reused) -> tanh -> gbuf.
//   XCD swizzle: xcd = p&7 owns a contiguous 8-t window -> t-halo L2 hits.
// Copy blocks [256, 256+392): NT float4 passthrough of the c>=128 half,
//   16 t's per thread; HBM stream overlaps the gate latency chains.
// ---------------------------------------------------------------------------
__global__ __launch_bounds__(1024) void gate_copy_kernel(
    const float* __restrict__ x,
    const float* __restrict__ w_l,
    const float* __restrict__ b_l,
    const float* __restrict__ w_r,
    const float* __restrict__ b_r,
    float* __restrict__ gbuf,
    float* __restrict__ out)
{
    constexpr int NGATE = 256;
    __shared__ float4 red[8][7][64];   // 57,344 B

    const int p = blockIdx.x;

    if (p >= NGATE) {
        // ---------------- copy path: c >= 128 ----------------
        const int qq     = p - NGATE;          // [0, 392)
        const int tchunk = qq / 98;
        const int bx2    = qq - tchunk * 98;
        const int tid    = 128 * HW4 + bx2 * 1024 + (int)threadIdx.x;
        const int t0     = tchunk * 16;

        const nt_float4* xn4 = (const nt_float4*)x;
        nt_float4*       on4 = (nt_float4*)out;
        const size_t ts = C_DIM * HW4;

        #pragma unroll 4
        for (int i = 0; i < 16; ++i) {
            const size_t idx = (size_t)(t0 + i) * ts + tid;
            nt_float4 v = __builtin_nontemporal_load(&xn4[idx]);
            __builtin_nontemporal_store(v, &on4[idx]);
        }
        return;
    }

    // ---------------- gate path ----------------
    const int xcd  = p & 7;
    const int r    = p >> 3;           // [0,32)
    const int tl   = r & 7;
    const int side = (r >> 3) & 1;
    const int hh   = (r >> 4) & 1;
    const int t    = xcd * 8 + tl;

    const int waveid = __builtin_amdgcn_readfirstlane((int)(threadIdx.x >> 6));
    const int lane = threadIdx.x & 63;
    const int wg   = lane & 15;
    const int rg   = lane >> 4;
    const bool act = (wg < 14);
    const int w0   = act ? wg * 4 : 52;
    const int r0   = hh * 28 + rg * 7;
    const bool have_l = (wg > 0);
    const bool have_r = (wg < 13);

    const float* wtab = (side ? w_r : w_l) + waveid * 4 * 27;  // wave-uniform
    const int c0 = side * 64 + waveid * 4;

    const int tm = (t + 63) & 63, tp = (t + 1) & 63;
    const float* tbase[3] = { x + (size_t)tm * CHW,
                              x + (size_t)t  * CHW,
                              x + (size_t)tp * CHW };

    float acc[7][4];
    #pragma unroll
    for (int j = 0; j < 7; ++j)
        #pragma unroll
        for (int k = 0; k < 4; ++k) acc[j][k] = 0.f;

    #pragma unroll 1
    for (int ci = 0; ci < 4; ++ci) {
        float wgt[27];
        #pragma unroll
        for (int k = 0; k < 27; ++k) wgt[k] = rfl(wtab[ci * 27 + k]);  // SGPRs

        #pragma unroll
        for (int dt = 0; dt < 3; ++dt) {
            const float* plane = tbase[dt] + (size_t)(c0 + ci) * HW;

            #pragma unroll
            for (int s9 = 0; s9 < 9; ++s9) {
                const int sr = r0 - 1 + s9;
                bool rv = true;
                int  srow = sr;
                if (s9 == 0)      { rv = (sr >= 0);     srow = rv ? sr : 0; }
                else if (s9 == 8) { rv = (sr < H_DIM);  srow = rv ? sr : (H_DIM - 1); }

                const float* row = plane + srow * W_DIM;
                float4 m  = *(const float4*)(row + w0);
                float  fl = __shfl_up(m.w, 1);    // lane-1's row[w0+3] == row[w0-1]
                float  fr = __shfl_down(m.x, 1);  // lane+1's row[w0]   == row[w0+4]

                float f0 = have_l ? fl : 0.f;
                float f1 = m.x, f2 = m.y, f3 = m.z, f4v = m.w;
                float f5 = have_r ? fr : 0.f;
                if ((s9 == 0 || s9 == 8) && !rv) {
                    f0 = 0.f; f1 = 0.f; f2 = 0.f; f3 = 0.f; f4v = 0.f; f5 = 0.f;
                }
                float f[6] = { f0, f1, f2, f3, f4v, f5 };

                const int jlo = (s9 >= 2) ? s9 - 2 : 0;
                const int jhi = (s9 <= 6) ? s9 : 6;
                #pragma unroll
                for (int j = jlo; j <= jhi; ++j) {
                    const int dh = s9 - j;
                    const float w0t = wgt[dt * 9 + dh * 3 + 0];
                    const float w1t = wgt[dt * 9 + dh * 3 + 1];
                    const float w2t = wgt[dt * 9 + dh * 3 + 2];
                    #pragma unroll
                    for (int k = 0; k < 4; ++k)
                        acc[j][k] += w0t * f[k] + w1t * f[k + 1] + w2t * f[k + 2];
                }
            }
        }
    }

    // ---- log-tree reduce over 16 waves (LDS slice buffer reused) ----
    #pragma unroll
    for (int n = 8; n >= 1; n >>= 1) {
        if (waveid >= n && waveid < 2 * n) {
            #pragma unroll
            for (int j = 0; j < 7; ++j) {
                float4 v; v.x = acc[j][0]; v.y = acc[j][1];
                          v.z = acc[j][2]; v.w = acc[j][3];
                red[waveid - n][j][lane] = v;
            }
        }
        __syncthreads();
        if (waveid < n) {
            #pragma unroll
            for (int j = 0; j < 7; ++j) {
                float4 v = red[waveid][j][lane];
                acc[j][0] += v.x; acc[j][1] += v.y;
                acc[j][2] += v.z; acc[j][3] += v.w;
            }
        }
        if (n > 1) __syncthreads();
    }

    if (waveid == 0 && act) {
        const float bias = side ? b_r[0] : b_l[0];
        float* pp = gbuf + (size_t)side * THW
                         + (size_t)t * HW + r0 * W_DIM + w0;
        #pragma unroll
        for (int j = 0; j < 7; ++j) {
            float4 v;
            v.x = tanhf(acc[j][0] + bias);
            v.y = tanhf(acc[j][1] + bias);
            v.z = tanhf(acc[j][2] + bias);
            v.w = tanhf(acc[j][3] + bias);
            *(float4*)(pp + j * W_DIM) = v;
        }
    }
}

// ---------------------------------------------------------------------------
// Combine (c < 128 only): thread owns (c,h,w4), iterates 16 t's carrying
// x/g in registers. NT stores (out never re-read).
// ---------------------------------------------------------------------------
__global__ __launch_bounds__(256) void combine_kernel(
    const float* __restrict__ x,
    const float* __restrict__ g,
    float* __restrict__ out)
{
    const int tid = blockIdx.x * 256 + threadIdx.x;   // c in [0,128)
    const int t0  = blockIdx.y * 16;
    const int c   = tid / HW4;
    const int gb  = tid - c * HW4;

    const float4* x4 = (const float4*)x;
    nt_float4*    on4 = (nt_float4*)out;
    const size_t  ts = C_DIM * HW4;
    const size_t  base = tid;

    if (c < 64) {
        const float4* gl4 = (const float4*)g;
        float4 xv = x4[(size_t)t0 * ts + base];
        float4 g0 = gl4[t0 * HW4 + gb];
        #pragma unroll 4
        for (int i = 0; i < 16; ++i) {
            const int t  = t0 + i;
            const int tp = (t + 1) & 63;
            float4 xn = x4[(size_t)tp * ts + base];
            float4 g1 = gl4[tp * HW4 + gb];
            nt_float4 r;
            r.x = xv.x - g0.x * xv.x + g1.x * xn.x;
            r.y = xv.y - g0.y * xv.y + g1.y * xn.y;
            r.z = xv.z - g0.z * xv.z + g1.z * xn.z;
            r.w = xv.w - g0.w * xv.w + g1.w * xn.w;
            __builtin_nontemporal_store(r, &on4[(size_t)t * ts + base]);
            xv = xn; g0 = g1;
        }
    } else {
        const float4* gr4 = (const float4*)(g + THW);
        const int tmi = (t0 + 63) & 63;
        float4 xm = x4[(size_t)tmi * ts + base];
        float4 gm = gr4[tmi * HW4 + gb];
        #pragma unroll 4
        for (int i = 0; i < 16; ++i) {
            const int t = t0 + i;
            float4 xv = x4[(size_t)t * ts + base];
            float4 g0 = gr4[t * HW4 + gb];
            nt_float4 r;
            r.x = xv.x - g0.x * xv.x + gm.x * xm.x;
            r.y = xv.y - g0.y * xv.y + gm.y * xm.y;
            r.z = xv.z - g0.z * xv.z + gm.z * xm.z;
            r.w = xv.w - g0.w * xv.w + gm.w * xm.w;
            __builtin_nontemporal_store(r, &on4[(size_t)t * ts + base]);
            xm = xv; gm = g0;
        }
    }
}

extern "C" void kernel_launch(void* const* d_in, const int* in_sizes, int n_in,
                              void* d_out, int out_size, void* d_ws, size_t ws_size,
                              hipStream_t stream) {
    const float* x   = (const float*)d_in[0];
    const float* w_l = (const float*)d_in[1];
    const float* b_l = (const float*)d_in[2];
    const float* w_r = (const float*)d_in[3];
    const float* b_r = (const float*)d_in[4];
    float* out  = (float*)d_out;
    float* gbuf = (float*)d_ws;                // 2 gate planes = 1.6 MB

    const int ngate = 256;
    const int ncopy = 392;                     // c>=128 half, 1024 thr, 16 t ea
    gate_copy_kernel<<<ngate + ncopy, 1024, 0, stream>>>(x, w_l, b_l, w_r, b_r,
                                                         gbuf, out);
    combine_kernel<<<dim3(392, 4), 256, 0, stream>>>(x, gbuf, out);
}

// Round 13
// 110.040 us; speedup vs baseline: 2.6324x; 2.6324x over previous
//
#include <hip/hip_runtime.h>
#include <hip/hip_cooperative_groups.h>
#include <math.h>

namespace cg = cooperative_groups;

#define T_DIM 64
#define C_DIM 256
#define H_DIM 56
#define W_DIM 56
#define HW    (H_DIM * W_DIM)        // 3136
#define HW4   (HW / 4)               // 784
#define CHW   (C_DIM * HW)
#define THW   (T_DIM * HW)           // 200704
#define PL4   (THW / 4)              // 50176 float4 per plane
#define TS4   (C_DIM * HW4)          // 200704 float4 per t-plane
#define NCOL  (128 * HW4)            // 100352 combine columns
#define NCOPY4 (T_DIM * NCOL)        // 6,422,528 copy float4s
#define GRID_F 1024
#define GSZ   (GRID_F * 256)

typedef float nt_float4 __attribute__((ext_vector_type(4)));

__device__ __forceinline__ float rfl(float v) {
    return __int_as_float(__builtin_amdgcn_readfirstlane(__float_as_int(v)));
}

// ===========================================================================
// Fused cooperative kernel: 1024 blocks x 256 threads (4 blocks/CU).
// A: gate partials (4 waves x 4ch, LDS-reduce -> 8 pbuf planes) + grid-stride
//    NT copy of c>=128; parity-swapped order for gate/copy overlap.
// B: reduce 8 planes + bias + tanh -> gbuf.   C: combine c<128.
// ===========================================================================
__global__ __launch_bounds__(256) void fused_all(
    const float* __restrict__ x,
    const float* __restrict__ w_l,
    const float* __restrict__ b_l,
    const float* __restrict__ w_r,
    const float* __restrict__ b_r,
    float* __restrict__ pbuf,
    float* __restrict__ gbuf,
    float* __restrict__ out)
{
    cg::grid_group grid = cg::this_grid();
    __shared__ float4 red[4][7][64];   // 28672 B

    const int p    = blockIdx.x;
    const int tid  = threadIdx.x;
    const int gtid = p * 256 + tid;

    // ---------------- phase A ----------------
    // gate geometry: xcd = p&7 owns t in [xcd*8, xcd*8+8)
    const int rr   = p >> 3;
    const int tl   = rr & 7;
    const int side = (rr >> 3) & 1;
    const int hh   = (rr >> 4) & 1;
    const int gq   = (rr >> 5) & 3;
    const int t    = (p & 7) * 8 + tl;

    const int waveid = __builtin_amdgcn_readfirstlane(tid >> 6);
    const int lane = tid & 63;
    const int wg   = lane & 15;
    const int rg   = lane >> 4;
    const bool act = (wg < 14);
    const int w0   = act ? wg * 4 : 52;
    const int r0   = hh * 28 + rg * 7;
    const bool have_l = (wg > 0);
    const bool have_r = (wg < 13);

    auto do_copy = [&]() {
        const nt_float4* xn4 = (const nt_float4*)x;
        nt_float4*       on4 = (nt_float4*)out;
        for (int i = gtid; i < NCOPY4; i += GSZ) {
            const int tt = i / NCOL;
            const int rc = i - tt * NCOL;
            const size_t idx = (size_t)tt * TS4 + NCOL + rc;
            nt_float4 v = __builtin_nontemporal_load(&xn4[idx]);
            __builtin_nontemporal_store(v, &on4[idx]);
        }
    };

    auto do_gate = [&]() {
        const int cw = gq * 16 + waveid * 4;          // channel base in half
        const float* wtab = (side ? w_r : w_l) + cw * 27;
        const int c0 = side * 64 + cw;

        const int tm = (t + 63) & 63, tp = (t + 1) & 63;
        const float* tbase[3] = { x + (size_t)tm * CHW,
                                  x + (size_t)t  * CHW,
                                  x + (size_t)tp * CHW };

        float acc[7][4];
        #pragma unroll
        for (int j = 0; j < 7; ++j)
            #pragma unroll
            for (int k = 0; k < 4; ++k) acc[j][k] = 0.f;

        #pragma unroll 1
        for (int ci = 0; ci < 4; ++ci) {
            float wgt[27];
            #pragma unroll
            for (int k = 0; k < 27; ++k) wgt[k] = rfl(wtab[ci * 27 + k]);

            #pragma unroll
            for (int dt = 0; dt < 3; ++dt) {
                const float* plane = tbase[dt] + (size_t)(c0 + ci) * HW;

                #pragma unroll
                for (int s9 = 0; s9 < 9; ++s9) {
                    const int sr = r0 - 1 + s9;
                    bool rv = true;
                    int  srow = sr;
                    if (s9 == 0)      { rv = (sr >= 0);     srow = rv ? sr : 0; }
                    else if (s9 == 8) { rv = (sr < H_DIM);  srow = rv ? sr : (H_DIM - 1); }

                    const float* row = plane + srow * W_DIM;
                    float4 m  = *(const float4*)(row + w0);
                    float  fl = __shfl_up(m.w, 1);
                    float  fr = __shfl_down(m.x, 1);

                    float f0 = have_l ? fl : 0.f;
                    float f1 = m.x, f2 = m.y, f3 = m.z, f4v = m.w;
                    float f5 = have_r ? fr : 0.f;
                    if ((s9 == 0 || s9 == 8) && !rv) {
                        f0 = 0.f; f1 = 0.f; f2 = 0.f; f3 = 0.f; f4v = 0.f; f5 = 0.f;
                    }
                    float f[6] = { f0, f1, f2, f3, f4v, f5 };

                    const int jlo = (s9 >= 2) ? s9 - 2 : 0;
                    const int jhi = (s9 <= 6) ? s9 : 6;
                    #pragma unroll
                    for (int j = jlo; j <= jhi; ++j) {
                        const int dh = s9 - j;
                        const float w0t = wgt[dt * 9 + dh * 3 + 0];
                        const float w1t = wgt[dt * 9 + dh * 3 + 1];
                        const float w2t = wgt[dt * 9 + dh * 3 + 2];
                        #pragma unroll
                        for (int k = 0; k < 4; ++k)
                            acc[j][k] += w0t * f[k] + w1t * f[k + 1] + w2t * f[k + 2];
                    }
                }
            }
        }

        #pragma unroll
        for (int j = 0; j < 7; ++j) {
            float4 v; v.x = acc[j][0]; v.y = acc[j][1];
                      v.z = acc[j][2]; v.w = acc[j][3];
            red[waveid][j][lane] = v;
        }
        __syncthreads();

        if (waveid == 0 && act) {
            const int sg = side * 4 + gq;
            float* pp = pbuf + (size_t)sg * THW
                             + (size_t)t * HW + r0 * W_DIM + w0;
            #pragma unroll
            for (int j = 0; j < 7; ++j) {
                float4 a = red[0][j][lane], b2 = red[1][j][lane];
                float4 c = red[2][j][lane], d  = red[3][j][lane];
                float4 v;
                v.x = (a.x + b2.x) + (c.x + d.x);
                v.y = (a.y + b2.y) + (c.y + d.y);
                v.z = (a.z + b2.z) + (c.z + d.z);
                v.w = (a.w + b2.w) + (c.w + d.w);
                *(float4*)(pp + j * W_DIM) = v;
            }
        }
    };

    if (p & 1) { do_copy(); do_gate(); }
    else       { do_gate(); do_copy(); }

    grid.sync();

    // ---------------- phase B: reduce + tanh -> gbuf ----------------
    if (gtid < PL4) {
        const float4* p4 = (const float4*)pbuf;
        float4* g4 = (float4*)gbuf;
        float4 a = {0.f,0.f,0.f,0.f}, b = {0.f,0.f,0.f,0.f};
        #pragma unroll
        for (int g = 0; g < 4; ++g) {
            float4 va = p4[(size_t)g       * PL4 + gtid];
            float4 vb = p4[(size_t)(4 + g) * PL4 + gtid];
            a.x += va.x; a.y += va.y; a.z += va.z; a.w += va.w;
            b.x += vb.x; b.y += vb.y; b.z += vb.z; b.w += vb.w;
        }
        const float bl = b_l[0], br = b_r[0];
        float4 gl, gr;
        gl.x = tanhf(a.x + bl); gl.y = tanhf(a.y + bl);
        gl.z = tanhf(a.z + bl); gl.w = tanhf(a.w + bl);
        gr.x = tanhf(b.x + br); gr.y = tanhf(b.y + br);
        gr.z = tanhf(b.z + br); gr.w = tanhf(b.w + br);
        g4[gtid]       = gl;
        g4[PL4 + gtid] = gr;
    }

    grid.sync();

    // ---------------- phase C: combine c < 128 ----------------
    if (gtid < 2 * NCOL) {
        const int chunk = (gtid >= NCOL);
        const int col   = gtid - chunk * NCOL;
        const int c     = col / HW4;
        const int gb    = col - c * HW4;
        const int t0    = chunk * 32;

        const float4* x4 = (const float4*)x;
        nt_float4*    on4 = (nt_float4*)out;
        const float4* g4 = (const float4*)gbuf;

        if (c < 64) {
            float4 xv = x4[(size_t)t0 * TS4 + col];
            float4 g0 = g4[t0 * HW4 + gb];
            #pragma unroll 4
            for (int i = 0; i < 32; ++i) {
                const int tt = t0 + i;
                const int tp2 = (tt + 1) & 63;
                float4 xn = x4[(size_t)tp2 * TS4 + col];
                float4 g1 = g4[tp2 * HW4 + gb];
                nt_float4 r;
                r.x = xv.x - g0.x * xv.x + g1.x * xn.x;
                r.y = xv.y - g0.y * xv.y + g1.y * xn.y;
                r.z = xv.z - g0.z * xv.z + g1.z * xn.z;
                r.w = xv.w - g0.w * xv.w + g1.w * xn.w;
                __builtin_nontemporal_store(r, &on4[(size_t)tt * TS4 + col]);
                xv = xn; g0 = g1;
            }
        } else {
            const float4* gr4 = g4 + PL4;
            const int tmi = (t0 + 63) & 63;
            float4 xm = x4[(size_t)tmi * TS4 + col];
            float4 gm = gr4[tmi * HW4 + gb];
            #pragma unroll 4
            for (int i = 0; i < 32; ++i) {
                const int tt = t0 + i;
                float4 xv = x4[(size_t)tt * TS4 + col];
                float4 g0 = gr4[tt * HW4 + gb];
                nt_float4 r;
                r.x = xv.x - g0.x * xv.x + gm.x * xm.x;
                r.y = xv.y - g0.y * xv.y + gm.y * xm.y;
                r.z = xv.z - g0.z * xv.z + gm.z * xm.z;
                r.w = xv.w - g0.w * xv.w + gm.w * xm.w;
                __builtin_nontemporal_store(r, &on4[(size_t)tt * TS4 + col]);
                xm = xv; gm = g0;
            }
        }
    }
}

// ===========================================================================
// Fallback path (proven R10 structure): gate+copy, reduce, combine.
// ===========================================================================
template<int S>
__global__ __launch_bounds__(256) void gate_copy_kernel(
    const float* __restrict__ x,
    const float* __restrict__ w_l,
    const float* __restrict__ w_r,
    float* __restrict__ pbuf,
    float* __restrict__ out)
{
    constexpr int CPG   = 64 / S;
    constexpr int NGATE = 2 * S * 32;

    const int p = blockIdx.x;

    if (p >= NGATE) {
        const int qq     = p - NGATE;
        const int tchunk = qq / 392;
        const int bx2    = qq - tchunk * 392;
        const int tid    = 128 * HW4 + bx2 * 256 + (int)threadIdx.x;
        const int t0     = tchunk * 16;

        const nt_float4* xn4 = (const nt_float4*)x;
        nt_float4*       on4 = (nt_float4*)out;

        #pragma unroll 4
        for (int i = 0; i < 16; ++i) {
            const size_t idx = (size_t)(t0 + i) * TS4 + tid;
            nt_float4 v = __builtin_nontemporal_load(&xn4[idx]);
            __builtin_nontemporal_store(v, &on4[idx]);
        }
        return;
    }

    const int xcd = p & 7;
    const int s   = p >> 3;
    const int sg  = xcd * (2 * S / 8) + (s >> 5);
    const int tq  = s & 31;
    const int side = sg / S;
    const int g    = sg & (S - 1);

    const int waveid = __builtin_amdgcn_readfirstlane((int)(threadIdx.x >> 6));
    const int hh = waveid & 1;
    const int t  = tq * 2 + (waveid >> 1);

    const int lane = threadIdx.x & 63;
    const int wg   = lane & 15;
    const int rg   = lane >> 4;
    const bool act = (wg < 14);
    const int w0   = act ? wg * 4 : 52;
    const int r0   = hh * 28 + rg * 7;
    const bool have_l = (wg > 0);
    const bool have_r = (wg < 13);

    const float* wtab = (side ? w_r : w_l) + g * CPG * 27;
    const int c0 = side * 64 + g * CPG;

    const int tm = (t + 63) & 63, tp = (t + 1) & 63;
    const float* tbase[3] = { x + (size_t)tm * CHW,
                              x + (size_t)t  * CHW,
                              x + (size_t)tp * CHW };

    float acc[7][4];
    #pragma unroll
    for (int j = 0; j < 7; ++j)
        #pragma unroll
        for (int k = 0; k < 4; ++k) acc[j][k] = 0.f;

    #pragma unroll 1
    for (int ci = 0; ci < CPG; ++ci) {
        float wgt[27];
        #pragma unroll
        for (int k = 0; k < 27; ++k) wgt[k] = rfl(wtab[ci * 27 + k]);

        #pragma unroll
        for (int dt = 0; dt < 3; ++dt) {
            const float* plane = tbase[dt] + (size_t)(c0 + ci) * HW;

            #pragma unroll
            for (int s9 = 0; s9 < 9; ++s9) {
                const int sr = r0 - 1 + s9;
                bool rv = true;
                int  srow = sr;
                if (s9 == 0)      { rv = (sr >= 0);     srow = rv ? sr : 0; }
                else if (s9 == 8) { rv = (sr < H_DIM);  srow = rv ? sr : (H_DIM - 1); }

                const float* row = plane + srow * W_DIM;
                float4 m  = *(const float4*)(row + w0);
                float  fl = __shfl_up(m.w, 1);
                float  fr = __shfl_down(m.x, 1);

                float f0 = have_l ? fl : 0.f;
                float f1 = m.x, f2 = m.y, f3 = m.z, f4v = m.w;
                float f5 = have_r ? fr : 0.f;
                if ((s9 == 0 || s9 == 8) && !rv) {
                    f0 = 0.f; f1 = 0.f; f2 = 0.f; f3 = 0.f; f4v = 0.f; f5 = 0.f;
                }
                float f[6] = { f0, f1, f2, f3, f4v, f5 };

                const int jlo = (s9 >= 2) ? s9 - 2 : 0;
                const int jhi = (s9 <= 6) ? s9 : 6;
                #pragma unroll
                for (int j = jlo; j <= jhi; ++j) {
                    const int dh = s9 - j;
                    const float w0t = wgt[dt * 9 + dh * 3 + 0];
                    const float w1t = wgt[dt * 9 + dh * 3 + 1];
                    const float w2t = wgt[dt * 9 + dh * 3 + 2];
                    #pragma unroll
                    for (int k = 0; k < 4; ++k)
                        acc[j][k] += w0t * f[k] + w1t * f[k + 1] + w2t * f[k + 2];
                }
            }
        }
    }

    if (act) {
        float* pp = pbuf + (size_t)sg * THW
                         + (size_t)t * HW + r0 * W_DIM + w0;
        #pragma unroll
        for (int j = 0; j < 7; ++j) {
            float4 v; v.x = acc[j][0]; v.y = acc[j][1]; v.z = acc[j][2]; v.w = acc[j][3];
            *(float4*)(pp + j * W_DIM) = v;
        }
    }
}

template<int S>
__global__ __launch_bounds__(256) void reduce_tanh_kernel(
    const float* __restrict__ pbuf,
    float* __restrict__ gbuf,
    const float* __restrict__ b_l,
    const float* __restrict__ b_r)
{
    const int i = blockIdx.x * 256 + threadIdx.x;
    const float4* p4 = (const float4*)pbuf;
    float4* g4 = (float4*)gbuf;

    float4 a = {0.f,0.f,0.f,0.f}, b = {0.f,0.f,0.f,0.f};
    #pragma unroll
    for (int g = 0; g < S; ++g) {
        float4 va = p4[(size_t)g       * PL4 + i];
        float4 vb = p4[(size_t)(S + g) * PL4 + i];
        a.x += va.x; a.y += va.y; a.z += va.z; a.w += va.w;
        b.x += vb.x; b.y += vb.y; b.z += vb.z; b.w += vb.w;
    }
    const float bl = b_l[0], br = b_r[0];
    float4 gl, gr;
    gl.x = tanhf(a.x + bl); gl.y = tanhf(a.y + bl);
    gl.z = tanhf(a.z + bl); gl.w = tanhf(a.w + bl);
    gr.x = tanhf(b.x + br); gr.y = tanhf(b.y + br);
    gr.z = tanhf(b.z + br); gr.w = tanhf(b.w + br);
    g4[i]       = gl;
    g4[PL4 + i] = gr;
}

__global__ __launch_bounds__(256) void combine_kernel(
    const float* __restrict__ x,
    const float* __restrict__ g,
    float* __restrict__ out)
{
    const int tid = blockIdx.x * 256 + threadIdx.x;
    const int t0  = blockIdx.y * 16;
    const int c   = tid / HW4;
    const int gb  = tid - c * HW4;

    const float4* x4 = (const float4*)x;
    nt_float4*    on4 = (nt_float4*)out;
    const size_t  base = tid;

    if (c < 64) {
        const float4* gl4 = (const float4*)g;
        float4 xv = x4[(size_t)t0 * TS4 + base];
        float4 g0 = gl4[t0 * HW4 + gb];
        #pragma unroll 4
        for (int i = 0; i < 16; ++i) {
            const int t  = t0 + i;
            const int tp = (t + 1) & 63;
            float4 xn = x4[(size_t)tp * TS4 + base];
            float4 g1 = gl4[tp * HW4 + gb];
            nt_float4 r;
            r.x = xv.x - g0.x * xv.x + g1.x * xn.x;
            r.y = xv.y - g0.y * xv.y + g1.y * xn.y;
            r.z = xv.z - g0.z * xv.z + g1.z * xn.z;
            r.w = xv.w - g0.w * xv.w + g1.w * xn.w;
            __builtin_nontemporal_store(r, &on4[(size_t)t * TS4 + base]);
            xv = xn; g0 = g1;
        }
    } else {
        const float4* gr4 = (const float4*)(g + THW);
        const int tmi = (t0 + 63) & 63;
        float4 xm = x4[(size_t)tmi * TS4 + base];
        float4 gm = gr4[tmi * HW4 + gb];
        #pragma unroll 4
        for (int i = 0; i < 16; ++i) {
            const int t = t0 + i;
            float4 xv = x4[(size_t)t * TS4 + base];
            float4 g0 = gr4[t * HW4 + gb];
            nt_float4 r;
            r.x = xv.x - g0.x * xv.x + gm.x * xm.x;
            r.y = xv.y - g0.y * xv.y + gm.y * xm.y;
            r.z = xv.z - g0.z * xv.z + gm.z * xm.z;
            r.w = xv.w - g0.w * xv.w + gm.w * xm.w;
            __builtin_nontemporal_store(r, &on4[(size_t)t * TS4 + base]);
            xm = xv; gm = g0;
        }
    }
}

extern "C" void kernel_launch(void* const* d_in, const int* in_sizes, int n_in,
                              void* d_out, int out_size, void* d_ws, size_t ws_size,
                              hipStream_t stream) {
    const float* x   = (const float*)d_in[0];
    const float* w_l = (const float*)d_in[1];
    const float* b_l = (const float*)d_in[2];
    const float* w_r = (const float*)d_in[3];
    const float* b_r = (const float*)d_in[4];
    float* out  = (float*)d_out;
    float* ws   = (float*)d_ws;

    // Try the cooperative fused path: needs 4 co-resident blocks/CU.
    int nb = 0;
    hipError_t oe = hipOccupancyMaxActiveBlocksPerMultiprocessor(
        &nb, reinterpret_cast<const void*>(&fused_all), 256, 0);
    const size_t plane_bytes = (size_t)THW * 4;
    bool try_coop = (oe == hipSuccess) && (nb >= 4) &&
                    (ws_size >= 10 * plane_bytes);

    if (try_coop) {
        float* pbuf = ws;                      // 8 planes
        float* gbuf = ws + (size_t)8 * THW;    // 2 planes
        void* args[8] = { (void*)&x, (void*)&w_l, (void*)&b_l,
                          (void*)&w_r, (void*)&b_r,
                          (void*)&pbuf, (void*)&gbuf, (void*)&out };
        hipError_t le = hipLaunchCooperativeKernel(
            reinterpret_cast<const void*>(&fused_all),
            dim3(GRID_F), dim3(256), args, 0, stream);
        if (le == hipSuccess) return;
    }

    // Fallback: proven three-kernel path (S=16).
    constexpr int S = 16;
    float* pbuf = ws;
    float* gbuf = ws + (size_t)(2 * S) * THW;
    const int ngate = 2 * S * 32;
    const int ncopy = 392 * 4;
    gate_copy_kernel<S><<<ngate + ncopy, 256, 0, stream>>>(x, w_l, w_r, pbuf, out);
    reduce_tanh_kernel<S><<<PL4 / 256, 256, 0, stream>>>(pbuf, gbuf, b_l, b_r);
    combine_kernel<<<dim3(392, 4), 256, 0, stream>>>(x, gbuf, out);
}